// Round 2
// baseline (701.432 us; speedup 1.0000x reference)
//
#include <hip/hip_runtime.h>
#include <hip/hip_bf16.h>

typedef __bf16 bf16_t;
typedef __bf16 bf16x8 __attribute__((ext_vector_type(8)));
typedef float f32x4 __attribute__((ext_vector_type(4)));

#define MFMA16(a, b, c) __builtin_amdgcn_mfma_f32_16x16x32_bf16(a, b, c, 0, 0, 0)

__device__ __forceinline__ void async_copy16(const void* g, void* l) {
  __builtin_amdgcn_global_load_lds(
      (const __attribute__((address_space(1))) void*)g,
      (__attribute__((address_space(3))) void*)l, 16, 0, 0);
}

// ---------------- cast f32 -> bf16 (8 elems/thread) ----------------
__global__ void cast_f32_bf16(const float* __restrict__ in, bf16_t* __restrict__ out, int n8) {
  int stride = gridDim.x * blockDim.x;
  for (int i = blockIdx.x * blockDim.x + threadIdx.x; i < n8; i += stride) {
    const float* p = in + (size_t)i * 8;
    f32x4 a = *(const f32x4*)p;
    f32x4 b = *(const f32x4*)(p + 4);
    bf16x8 o;
    o[0] = (bf16_t)a[0]; o[1] = (bf16_t)a[1]; o[2] = (bf16_t)a[2]; o[3] = (bf16_t)a[3];
    o[4] = (bf16_t)b[0]; o[5] = (bf16_t)b[1]; o[6] = (bf16_t)b[2]; o[7] = (bf16_t)b[3];
    *(bf16x8*)(out + (size_t)i * 8) = o;
  }
}

// ---------------- RoPE (in-place on q,k) ----------------
// id -> row = (b*H+h)*T + t, dp in [0,64)
__global__ void rope_kernel(bf16_t* __restrict__ q, bf16_t* __restrict__ k) {
  int id = blockIdx.x * blockDim.x + threadIdx.x;
  int dp = id & 63;
  int row = id >> 6;
  int t = row & 2047;
  float inv = expf(-0.14391156831212787f * (float)dp);  // ln(10000)/64
  float ang = (float)t * inv;
  float sv = sinf(ang), cv = cosf(ang);
  size_t base = (size_t)row * 128;
  float q1 = (float)q[base + dp], q2 = (float)q[base + dp + 64];
  q[base + dp]      = (bf16_t)(q1 * cv - q2 * sv);
  q[base + dp + 64] = (bf16_t)(q2 * cv + q1 * sv);
  float k1 = (float)k[base + dp], k2 = (float)k[base + dp + 64];
  k[base + dp]      = (bf16_t)(k1 * cv - k2 * sv);
  k[base + dp + 64] = (bf16_t)(k2 * cv + k1 * sv);
}

// ---------------- GEMM: C[m][n] = sum_k A[m][k] * Bw[n][k]  (both K-major bf16) ----
// MODE 0: write f32 C row-major [M][N]
// MODE 1: scatter to q/k (b,h,t,d) and vt (b,h,d,t), bf16
template <int MODE>
__global__ __launch_bounds__(256) void gemm_bt(
    const bf16_t* __restrict__ A, const bf16_t* __restrict__ Bw, float* __restrict__ C,
    bf16_t* __restrict__ qo, bf16_t* __restrict__ ko, bf16_t* __restrict__ vto,
    int M, int N, int K) {
  __shared__ bf16_t lds[2][2][128 * 32];  // [buf][A/B][row][32] linear, 32 KB
  int tid = threadIdx.x;
  int w = tid >> 6, lane = tid & 63;
  int wm = w >> 1, wn = w & 1;
  int mr = lane & 15, kg = lane >> 4;
  int row0 = blockIdx.y * 128;
  int col0 = blockIdx.x * 128;

  auto stage = [&](int buf, int t) {
#pragma unroll
    for (int it = 0; it < 2; ++it) {
      int chunk = it * 256 + tid;          // 0..511
      int r = chunk >> 2, cb = (chunk & 3) * 8;
      async_copy16(A + (size_t)(row0 + r) * K + t * 32 + cb, &lds[buf][0][chunk * 8]);
    }
#pragma unroll
    for (int it = 0; it < 2; ++it) {
      int chunk = it * 256 + tid;
      int r = chunk >> 2, cb = (chunk & 3) * 8;
      async_copy16(Bw + (size_t)(col0 + r) * K + t * 32 + cb, &lds[buf][1][chunk * 8]);
    }
  };

  f32x4 zero = {0.f, 0.f, 0.f, 0.f};
  f32x4 acc[4][4];
#pragma unroll
  for (int i = 0; i < 4; ++i)
#pragma unroll
    for (int jn = 0; jn < 4; ++jn) acc[i][jn] = zero;

  int nt = K / 32, cur = 0;
  stage(0, 0);
  for (int t = 0; t < nt; ++t) {
    __syncthreads();  // staging of buf[cur] complete; prev compute done
    if (t + 1 < nt) stage(cur ^ 1, t + 1);
    const bf16_t* As = &lds[cur][0][0];
    const bf16_t* Bs = &lds[cur][1][0];
    bf16x8 af[4], bfr[4];
#pragma unroll
    for (int i = 0; i < 4; ++i)
      af[i] = *(const bf16x8*)(As + (wm * 64 + i * 16 + mr) * 32 + kg * 8);
#pragma unroll
    for (int i = 0; i < 4; ++i)
      bfr[i] = *(const bf16x8*)(Bs + (wn * 64 + i * 16 + mr) * 32 + kg * 8);
#pragma unroll
    for (int i = 0; i < 4; ++i)
#pragma unroll
      for (int jn = 0; jn < 4; ++jn)
        acc[i][jn] = MFMA16(af[i], bfr[jn], acc[i][jn]);
    cur ^= 1;
  }

  if (MODE == 0) {
#pragma unroll
    for (int i = 0; i < 4; ++i)
#pragma unroll
      for (int jn = 0; jn < 4; ++jn)
#pragma unroll
        for (int jj = 0; jj < 4; ++jj) {
          int row = row0 + wm * 64 + i * 16 + kg * 4 + jj;
          int col = col0 + wn * 64 + jn * 16 + mr;
          C[(size_t)row * N + col] = acc[i][jn][jj];
        }
  } else {
#pragma unroll
    for (int i = 0; i < 4; ++i)
#pragma unroll
      for (int jn = 0; jn < 4; ++jn)
#pragma unroll
        for (int jj = 0; jj < 4; ++jj) {
          int row = row0 + wm * 64 + i * 16 + kg * 4 + jj;
          int b = row >> 11, tpos = row & 2047;
          int o = col0 + wn * 64 + jn * 16 + mr;
          int s = o >> 11, h = (o >> 7) & 15, d = o & 127;
          bf16_t val = (bf16_t)acc[i][jn][jj];
          if (s == 0)
            qo[(((size_t)b * 16 + h) * 2048 + tpos) * 128 + d] = val;
          else if (s == 1)
            ko[(((size_t)b * 16 + h) * 2048 + tpos) * 128 + d] = val;
          else
            vto[(((size_t)b * 16 + h) * 128 + d) * 2048 + tpos] = val;
        }
  }
}

// ---------------- causal flash attention ----------------
// grid (T/64, B*H), block 256 = 4 waves; wave owns 16 q-rows.
// q,k: [bh][t][128] bf16 (rope'd); vt: [bh][128][t] bf16
// out (matches reference transpose(0,2,1,3).reshape(B,T,C) SCRAMBLE):
//   og[b*2048 + h*128 + (t>>4)][(t&15)*128 + d]
__global__ __launch_bounds__(256) void attn_kernel(
    const bf16_t* __restrict__ qg, const bf16_t* __restrict__ kgl,
    const bf16_t* __restrict__ vtg, bf16_t* __restrict__ og) {
  __shared__ __align__(16) bf16_t plds[4][1024];  // per-wave swizzled P [16][64]
  const int T = 2048;
  int tid = threadIdx.x;
  int w = tid >> 6, lane = tid & 63;
  int mr = lane & 15, kg = lane >> 4;
  int bh = blockIdx.y;
  int qb = blockIdx.x;
  int qr0 = qb * 64 + w * 16;
  const bf16_t* Q = qg + (size_t)bh * T * 128;
  const bf16_t* K = kgl + (size_t)bh * T * 128;
  const bf16_t* Vt = vtg + (size_t)bh * 128 * T;

  bf16x8 qf[4];
#pragma unroll
  for (int db = 0; db < 4; ++db)
    qf[db] = *(const bf16x8*)(Q + (size_t)(qr0 + mr) * 128 + db * 32 + kg * 8);

  f32x4 zero = {0.f, 0.f, 0.f, 0.f};
  f32x4 acc[8];
#pragma unroll
  for (int d2 = 0; d2 < 8; ++d2) acc[d2] = zero;
  float mrun[4] = {-1e30f, -1e30f, -1e30f, -1e30f};
  float lrun[4] = {0.f, 0.f, 0.f, 0.f};
  const float scale = 0.08838834764831845f;  // 1/sqrt(128)
  bf16_t* P = &plds[w][0];

  for (int j = 0; j <= qb; ++j) {
    int kb = j * 64;
    // ---- S = Q K^T ----
    f32x4 s[4];
#pragma unroll
    for (int ntl = 0; ntl < 4; ++ntl) {
      s[ntl] = zero;
      const bf16_t* kr = K + (size_t)(kb + ntl * 16 + mr) * 128 + kg * 8;
#pragma unroll
      for (int db = 0; db < 4; ++db) {
        bf16x8 kf = *(const bf16x8*)(kr + db * 32);
        s[ntl] = MFMA16(qf[db], kf, s[ntl]);
      }
    }
    // ---- scale + causal mask + row max ----
    float pv[4][4];
    float tmax[4] = {-1e30f, -1e30f, -1e30f, -1e30f};
    bool diag = (j == qb);
#pragma unroll
    for (int ntl = 0; ntl < 4; ++ntl)
#pragma unroll
      for (int jj = 0; jj < 4; ++jj) {
        float v = s[ntl][jj] * scale;
        if (diag && (kb + ntl * 16 + mr) > (qr0 + kg * 4 + jj)) v = -1e30f;
        pv[ntl][jj] = v;
        tmax[jj] = fmaxf(tmax[jj], v);
      }
#pragma unroll
    for (int m = 1; m < 16; m <<= 1)
#pragma unroll
      for (int jj = 0; jj < 4; ++jj)
        tmax[jj] = fmaxf(tmax[jj], __shfl_xor(tmax[jj], m, 64));
    float corr[4], rs[4];
#pragma unroll
    for (int jj = 0; jj < 4; ++jj) {
      float mn = fmaxf(mrun[jj], tmax[jj]);
      corr[jj] = __expf(mrun[jj] - mn);
      mrun[jj] = mn;
      rs[jj] = 0.f;
    }
#pragma unroll
    for (int ntl = 0; ntl < 4; ++ntl)
#pragma unroll
      for (int jj = 0; jj < 4; ++jj) {
        float p = __expf(pv[ntl][jj] - mrun[jj]);
        pv[ntl][jj] = p;
        rs[jj] += p;
      }
#pragma unroll
    for (int m = 1; m < 16; m <<= 1)
#pragma unroll
      for (int jj = 0; jj < 4; ++jj) rs[jj] += __shfl_xor(rs[jj], m, 64);
#pragma unroll
    for (int jj = 0; jj < 4; ++jj) lrun[jj] = lrun[jj] * corr[jj] + rs[jj];
#pragma unroll
    for (int d2 = 0; d2 < 8; ++d2)
#pragma unroll
      for (int jj = 0; jj < 4; ++jj) acc[d2][jj] *= corr[jj];
    // ---- write P to LDS (XOR swizzle: byte ^= (row&7)<<4) ----
#pragma unroll
    for (int ntl = 0; ntl < 4; ++ntl)
#pragma unroll
      for (int jj = 0; jj < 4; ++jj) {
        int rr = kg * 4 + jj;
        int cbyte = (mr + ntl * 16) * 2;
        *(bf16_t*)((char*)P + rr * 128 + (cbyte ^ ((rr & 7) << 4))) = (bf16_t)pv[ntl][jj];
      }
    // ---- O += P V ----
#pragma unroll
    for (int ks = 0; ks < 2; ++ks) {
      int cb = (ks * 32 + kg * 8) * 2;
      bf16x8 pa = *(const bf16x8*)((const char*)P + mr * 128 + (cb ^ ((mr & 7) << 4)));
#pragma unroll
      for (int d2 = 0; d2 < 8; ++d2) {
        bf16x8 vf = *(const bf16x8*)(Vt + (size_t)(d2 * 16 + mr) * T + kb + ks * 32 + kg * 8);
        acc[d2] = MFMA16(pa, vf, acc[d2]);
      }
    }
  }
  // ---- epilogue: O /= l, store bf16 in the reference's scrambled layout ----
  int b = bh >> 4, h = bh & 15;
#pragma unroll
  for (int jj = 0; jj < 4; ++jj) {
    float invl = 1.0f / lrun[jj];
    int t = qr0 + kg * 4 + jj;
    size_t row = (size_t)b * 2048 + h * 128 + (t >> 4);
    bf16_t* orow = og + row * 2048 + (t & 15) * 128;
#pragma unroll
    for (int d2 = 0; d2 < 8; ++d2)
      orow[d2 * 16 + mr] = (bf16_t)(acc[d2][jj] * invl);
  }
}

extern "C" void kernel_launch(void* const* d_in, const int* in_sizes, int n_in,
                              void* d_out, int out_size, void* d_ws, size_t ws_size,
                              hipStream_t stream) {
  const float* x = (const float*)d_in[0];      // [2,2048,2048]
  const float* wqkv = (const float*)d_in[1];   // [6144,2048]
  const float* wproj = (const float*)d_in[2];  // [2048,2048]
  float* out = (float*)d_out;                  // [2,2048,2048]
  char* ws = (char*)d_ws;

  const size_t OFF_WQKV = 16777216;   // after xb (16.8 MB)
  const size_t OFF_Q = 41943040;      // after wqkvb (25.2 MB)
  const size_t OFF_K = 58720256;
  const size_t OFF_VT = 75497472;     // ends at 92274688

  bf16_t* xb = (bf16_t*)(ws);
  bf16_t* wqkvb = (bf16_t*)(ws + OFF_WQKV);
  bf16_t* g_q = (bf16_t*)(ws + OFF_Q);
  bf16_t* g_k = (bf16_t*)(ws + OFF_K);
  bf16_t* g_vt = (bf16_t*)(ws + OFF_VT);
  bf16_t* g_att = (bf16_t*)(ws);               // alias xb (dead after gemm1)
  bf16_t* wprojb = (bf16_t*)(ws + OFF_WQKV);   // alias wqkvb (dead after gemm1)

  // 1. casts
  cast_f32_bf16<<<2048, 256, 0, stream>>>(x, xb, 8388608 / 8);
  cast_f32_bf16<<<2048, 256, 0, stream>>>(wqkv, wqkvb, 12582912 / 8);
  // 2. qkv gemm, scatter to q/k/vt
  gemm_bt<1><<<dim3(48, 32), 256, 0, stream>>>(xb, wqkvb, nullptr, g_q, g_k, g_vt,
                                               4096, 6144, 2048);
  // 3. rope in-place on q,k
  rope_kernel<<<16384, 256, 0, stream>>>(g_q, g_k);
  // 4. cast w_proj (into wqkvb's space — gemm1 done)
  cast_f32_bf16<<<2048, 256, 0, stream>>>(wproj, wprojb, 4194304 / 8);
  // 5. causal flash attention
  attn_kernel<<<dim3(32, 32), 256, 0, stream>>>(g_q, g_k, g_vt, g_att);
  // 6. output projection (f32 out)
  gemm_bt<0><<<dim3(16, 32), 256, 0, stream>>>(g_att, wprojb, out, nullptr, nullptr,
                                               nullptr, 4096, 2048, 2048);
}

// Round 3
// 311.794 us; speedup vs baseline: 2.2497x; 2.2497x over previous
//
#include <hip/hip_runtime.h>
#include <hip/hip_bf16.h>

typedef __bf16 bf16_t;
typedef __bf16 bf16x8 __attribute__((ext_vector_type(8)));
typedef float f32x4 __attribute__((ext_vector_type(4)));

#define MFMA16(a, b, c) __builtin_amdgcn_mfma_f32_16x16x32_bf16(a, b, c, 0, 0, 0)

__device__ __forceinline__ void async_copy16(const void* g, void* l) {
  __builtin_amdgcn_global_load_lds(
      (const __attribute__((address_space(1))) void*)g,
      (__attribute__((address_space(3))) void*)l, 16, 0, 0);
}

// ---------------- cast f32 -> bf16 (8 elems/thread) ----------------
__global__ void cast_f32_bf16(const float* __restrict__ in, bf16_t* __restrict__ out, int n8) {
  int stride = gridDim.x * blockDim.x;
  for (int i = blockIdx.x * blockDim.x + threadIdx.x; i < n8; i += stride) {
    const float* p = in + (size_t)i * 8;
    f32x4 a = *(const f32x4*)p;
    f32x4 b = *(const f32x4*)(p + 4);
    bf16x8 o;
    o[0] = (bf16_t)a[0]; o[1] = (bf16_t)a[1]; o[2] = (bf16_t)a[2]; o[3] = (bf16_t)a[3];
    o[4] = (bf16_t)b[0]; o[5] = (bf16_t)b[1]; o[6] = (bf16_t)b[2]; o[7] = (bf16_t)b[3];
    *(bf16x8*)(out + (size_t)i * 8) = o;
  }
}

// ---------------- RoPE (in-place on q,k) ----------------
__global__ void rope_kernel(bf16_t* __restrict__ q, bf16_t* __restrict__ k) {
  int id = blockIdx.x * blockDim.x + threadIdx.x;
  int dp = id & 63;
  int row = id >> 6;
  int t = row & 2047;
  float inv = expf(-0.14391156831212787f * (float)dp);  // ln(10000)/64
  float ang = (float)t * inv;
  float sv = sinf(ang), cv = cosf(ang);
  size_t base = (size_t)row * 128;
  float q1 = (float)q[base + dp], q2 = (float)q[base + dp + 64];
  q[base + dp]      = (bf16_t)(q1 * cv - q2 * sv);
  q[base + dp + 64] = (bf16_t)(q2 * cv + q1 * sv);
  float k1 = (float)k[base + dp], k2 = (float)k[base + dp + 64];
  k[base + dp]      = (bf16_t)(k1 * cv - k2 * sv);
  k[base + dp + 64] = (bf16_t)(k2 * cv + k1 * sv);
}

// ---------------- GEMM: C[m][n] = sum_k A[m][k] * Bw[n][k] ----------------
template <int MODE>
__global__ __launch_bounds__(256) void gemm_bt(
    const bf16_t* __restrict__ A, const bf16_t* __restrict__ Bw, float* __restrict__ C,
    bf16_t* __restrict__ qo, bf16_t* __restrict__ ko, bf16_t* __restrict__ vto,
    int M, int N, int K) {
  __shared__ bf16_t lds[2][2][128 * 32];
  int tid = threadIdx.x;
  int w = tid >> 6, lane = tid & 63;
  int wm = w >> 1, wn = w & 1;
  int mr = lane & 15, kg = lane >> 4;
  int row0 = blockIdx.y * 128;
  int col0 = blockIdx.x * 128;

  auto stage = [&](int buf, int t) {
#pragma unroll
    for (int it = 0; it < 2; ++it) {
      int chunk = it * 256 + tid;
      int r = chunk >> 2, cb = (chunk & 3) * 8;
      async_copy16(A + (size_t)(row0 + r) * K + t * 32 + cb, &lds[buf][0][chunk * 8]);
    }
#pragma unroll
    for (int it = 0; it < 2; ++it) {
      int chunk = it * 256 + tid;
      int r = chunk >> 2, cb = (chunk & 3) * 8;
      async_copy16(Bw + (size_t)(col0 + r) * K + t * 32 + cb, &lds[buf][1][chunk * 8]);
    }
  };

  f32x4 zero = {0.f, 0.f, 0.f, 0.f};
  f32x4 acc[4][4];
#pragma unroll
  for (int i = 0; i < 4; ++i)
#pragma unroll
    for (int jn = 0; jn < 4; ++jn) acc[i][jn] = zero;

  int nt = K / 32, cur = 0;
  stage(0, 0);
  for (int t = 0; t < nt; ++t) {
    __syncthreads();
    if (t + 1 < nt) stage(cur ^ 1, t + 1);
    const bf16_t* As = &lds[cur][0][0];
    const bf16_t* Bs = &lds[cur][1][0];
    bf16x8 af[4], bfr[4];
#pragma unroll
    for (int i = 0; i < 4; ++i)
      af[i] = *(const bf16x8*)(As + (wm * 64 + i * 16 + mr) * 32 + kg * 8);
#pragma unroll
    for (int i = 0; i < 4; ++i)
      bfr[i] = *(const bf16x8*)(Bs + (wn * 64 + i * 16 + mr) * 32 + kg * 8);
#pragma unroll
    for (int i = 0; i < 4; ++i)
#pragma unroll
      for (int jn = 0; jn < 4; ++jn)
        acc[i][jn] = MFMA16(af[i], bfr[jn], acc[i][jn]);
    cur ^= 1;
  }

  if (MODE == 0) {
#pragma unroll
    for (int i = 0; i < 4; ++i)
#pragma unroll
      for (int jn = 0; jn < 4; ++jn)
#pragma unroll
        for (int jj = 0; jj < 4; ++jj) {
          int row = row0 + wm * 64 + i * 16 + kg * 4 + jj;
          int col = col0 + wn * 64 + jn * 16 + mr;
          C[(size_t)row * N + col] = acc[i][jn][jj];
        }
  } else {
#pragma unroll
    for (int i = 0; i < 4; ++i)
#pragma unroll
      for (int jn = 0; jn < 4; ++jn)
#pragma unroll
        for (int jj = 0; jj < 4; ++jj) {
          int row = row0 + wm * 64 + i * 16 + kg * 4 + jj;
          int b = row >> 11, tpos = row & 2047;
          int o = col0 + wn * 64 + jn * 16 + mr;
          int s = o >> 11, h = (o >> 7) & 15, d = o & 127;
          bf16_t val = (bf16_t)acc[i][jn][jj];
          if (s == 0)
            qo[(((size_t)b * 16 + h) * 2048 + tpos) * 128 + d] = val;
          else if (s == 1)
            ko[(((size_t)b * 16 + h) * 2048 + tpos) * 128 + d] = val;
          else
            vto[(((size_t)b * 16 + h) * 128 + d) * 2048 + tpos] = val;
        }
  }
}

// ---------------- causal flash attention (v2) ----------------
// grid (16, B*H): block handles q-tile pair {31-bx, bx} sequentially -> 33 tile-iters each.
// K/V tiles staged once per block in LDS (global_load_lds, double-buffered, XOR-swizzled).
// XCD-chunked role swizzle: each XCD serves 4 heads (K+V = 4MB = one L2).
__global__ __launch_bounds__(256) void attn_kernel(
    const bf16_t* __restrict__ qg, const bf16_t* __restrict__ kgl,
    const bf16_t* __restrict__ vtg, bf16_t* __restrict__ og) {
  __shared__ __align__(16) bf16_t Ks[2][64 * 128];   // [buf][k-row][d], 256B rows, swizzled
  __shared__ __align__(16) bf16_t Vs[2][128 * 64];   // [buf][d][t], 128B rows, swizzled
  __shared__ __align__(16) bf16_t plds[4][1024];     // per-wave P [16][64], swizzled
  const int T = 2048;
  int tid = threadIdx.x;
  int w = tid >> 6, lane = tid & 63;
  int mr = lane & 15, kg = lane >> 4;
  int swz = (mr & 7) << 4;

  // XCD-chunked bijective role swizzle (nwg=512, 8 XCDs)
  int L = blockIdx.y * 16 + blockIdx.x;
  int role = (L & 7) * 64 + (L >> 3);
  int bx = role & 15, bh = role >> 4;

  const bf16_t* Q = qg + (size_t)bh * T * 128;
  const bf16_t* K = kgl + (size_t)bh * T * 128;
  const bf16_t* Vt = vtg + (size_t)bh * 128 * T;

  // thread-constant staging offsets (inverse-swizzled global source, linear LDS dest)
  int sb = tid * 16;                       // byte offset within a 4KB issue chunk
  int krl = sb >> 8;                       // K local row 0..15
  int kc = (sb & 255) ^ ((krl & 7) << 4);
  size_t ksrc = (size_t)krl * 128 + (kc >> 1);
  int vdl = sb >> 7;                       // V local d-row 0..31
  int vc = (sb & 127) ^ ((vdl & 7) << 4);
  size_t vsrc = (size_t)vdl * 2048 + (vc >> 1);

  auto stage = [&](int buf, int kb) {
#pragma unroll
    for (int it = 0; it < 4; ++it)
      async_copy16(K + (size_t)(kb + it * 16) * 128 + ksrc, &Ks[buf][it * 2048 + tid * 8]);
#pragma unroll
    for (int it = 0; it < 4; ++it)
      async_copy16(Vt + (size_t)it * 65536 + kb + vsrc, &Vs[buf][it * 2048 + tid * 8]);
  };

  const float cscale = 0.12751744f;  // (1/sqrt(128)) * log2(e)
  f32x4 zero = {0.f, 0.f, 0.f, 0.f};
  bf16_t* P = &plds[w][0];
  int b = bh >> 4, h = bh & 15;

#pragma unroll 1
  for (int ph = 0; ph < 2; ++ph) {
    int qb = ph ? bx : (31 - bx);
    int qr0 = qb * 64 + w * 16;
    bf16x8 qf[4];
#pragma unroll
    for (int db = 0; db < 4; ++db)
      qf[db] = *(const bf16x8*)(Q + (size_t)(qr0 + mr) * 128 + db * 32 + kg * 8);

    f32x4 acc[8];
#pragma unroll
    for (int d2 = 0; d2 < 8; ++d2) acc[d2] = zero;
    float mrun[4] = {-1e30f, -1e30f, -1e30f, -1e30f};
    float lrun[4] = {0.f, 0.f, 0.f, 0.f};

    int nj = qb + 1;
    __syncthreads();  // Ks/Vs safe to reuse across phases
    stage(0, 0);
    int cur = 0;
#pragma unroll 1
    for (int j = 0; j < nj; ++j) {
      __syncthreads();  // staging of buf[cur] complete; prev compute done
      if (j + 1 < nj) stage(cur ^ 1, (j + 1) * 64);
      const char* KsB = (const char*)&Ks[cur][0];
      const char* VsB = (const char*)&Vs[cur][0];
      int kb = j * 64;
      // ---- S = Q K^T ----
      f32x4 s[4];
#pragma unroll
      for (int ntl = 0; ntl < 4; ++ntl) {
        s[ntl] = zero;
        int rowb = (ntl * 16 + mr) * 256;
#pragma unroll
        for (int db = 0; db < 4; ++db) {
          bf16x8 kf = *(const bf16x8*)(KsB + rowb + ((db * 64 + kg * 16) ^ swz));
          s[ntl] = MFMA16(qf[db], kf, s[ntl]);
        }
      }
      // ---- scale(+log2e) + causal mask + row max ----
      float pvv[4][4];
      float tmax[4] = {-3e38f, -3e38f, -3e38f, -3e38f};
      bool diag = (j == qb);
#pragma unroll
      for (int ntl = 0; ntl < 4; ++ntl)
#pragma unroll
        for (int jj = 0; jj < 4; ++jj) {
          float v = s[ntl][jj] * cscale;
          if (diag && (kb + ntl * 16 + mr) > (qr0 + kg * 4 + jj)) v = -1e30f;
          pvv[ntl][jj] = v;
          tmax[jj] = fmaxf(tmax[jj], v);
        }
#pragma unroll
      for (int m = 1; m < 16; m <<= 1)
#pragma unroll
        for (int jj = 0; jj < 4; ++jj)
          tmax[jj] = fmaxf(tmax[jj], __shfl_xor(tmax[jj], m, 64));
      // ---- defer-max (T13): rescale only when max grew > 8 (in log2 units) ----
      bool ok = true;
#pragma unroll
      for (int jj = 0; jj < 4; ++jj) ok &= (tmax[jj] <= mrun[jj] + 8.0f);
      if (!__all(ok)) {
#pragma unroll
        for (int jj = 0; jj < 4; ++jj) {
          float mn = fmaxf(mrun[jj], tmax[jj]);
          float corr = __builtin_amdgcn_exp2f(mrun[jj] - mn);
          mrun[jj] = mn;
          lrun[jj] *= corr;
#pragma unroll
          for (int d2 = 0; d2 < 8; ++d2) acc[d2][jj] *= corr;
        }
      }
      float rs[4] = {0.f, 0.f, 0.f, 0.f};
#pragma unroll
      for (int ntl = 0; ntl < 4; ++ntl)
#pragma unroll
        for (int jj = 0; jj < 4; ++jj) {
          float p = __builtin_amdgcn_exp2f(pvv[ntl][jj] - mrun[jj]);
          pvv[ntl][jj] = p;
          rs[jj] += p;
        }
#pragma unroll
      for (int m = 1; m < 16; m <<= 1)
#pragma unroll
        for (int jj = 0; jj < 4; ++jj) rs[jj] += __shfl_xor(rs[jj], m, 64);
#pragma unroll
      for (int jj = 0; jj < 4; ++jj) lrun[jj] += rs[jj];
      // ---- write P to per-wave LDS (XOR swizzle) ----
#pragma unroll
      for (int ntl = 0; ntl < 4; ++ntl)
#pragma unroll
        for (int jj = 0; jj < 4; ++jj) {
          int rr = kg * 4 + jj;
          int cbyte = (mr + ntl * 16) * 2;
          *(bf16_t*)((char*)P + rr * 128 + (cbyte ^ ((rr & 7) << 4))) = (bf16_t)pvv[ntl][jj];
        }
      // ---- O += P V ----
#pragma unroll
      for (int ks = 0; ks < 2; ++ks) {
        int cb = (ks * 32 + kg * 8) * 2;
        bf16x8 pa = *(const bf16x8*)((const char*)P + mr * 128 + (cb ^ ((mr & 7) << 4)));
#pragma unroll
        for (int d2 = 0; d2 < 8; ++d2) {
          bf16x8 vf = *(const bf16x8*)(VsB + (d2 * 16 + mr) * 128 + ((ks * 64 + kg * 16) ^ swz));
          acc[d2] = MFMA16(pa, vf, acc[d2]);
        }
      }
      cur ^= 1;
    }
    // ---- epilogue: O /= l, store in the reference's scrambled layout ----
#pragma unroll
    for (int jj = 0; jj < 4; ++jj) {
      float invl = 1.0f / lrun[jj];
      int t = qr0 + kg * 4 + jj;
      size_t row = (size_t)b * 2048 + h * 128 + (t >> 4);
      bf16_t* orow = og + row * 2048 + (t & 15) * 128;
#pragma unroll
      for (int d2 = 0; d2 < 8; ++d2)
        orow[d2 * 16 + mr] = (bf16_t)(acc[d2][jj] * invl);
    }
  }
}

extern "C" void kernel_launch(void* const* d_in, const int* in_sizes, int n_in,
                              void* d_out, int out_size, void* d_ws, size_t ws_size,
                              hipStream_t stream) {
  const float* x = (const float*)d_in[0];      // [2,2048,2048]
  const float* wqkv = (const float*)d_in[1];   // [6144,2048]
  const float* wproj = (const float*)d_in[2];  // [2048,2048]
  float* out = (float*)d_out;                  // [2,2048,2048]
  char* ws = (char*)d_ws;

  const size_t OFF_WQKV = 16777216;
  const size_t OFF_Q = 41943040;
  const size_t OFF_K = 58720256;
  const size_t OFF_VT = 75497472;

  bf16_t* xb = (bf16_t*)(ws);
  bf16_t* wqkvb = (bf16_t*)(ws + OFF_WQKV);
  bf16_t* g_q = (bf16_t*)(ws + OFF_Q);
  bf16_t* g_k = (bf16_t*)(ws + OFF_K);
  bf16_t* g_vt = (bf16_t*)(ws + OFF_VT);
  bf16_t* g_att = (bf16_t*)(ws);               // alias xb (dead after gemm1)
  bf16_t* wprojb = (bf16_t*)(ws + OFF_WQKV);   // alias wqkvb (dead after gemm1)

  cast_f32_bf16<<<2048, 256, 0, stream>>>(x, xb, 8388608 / 8);
  cast_f32_bf16<<<2048, 256, 0, stream>>>(wqkv, wqkvb, 12582912 / 8);
  gemm_bt<1><<<dim3(48, 32), 256, 0, stream>>>(xb, wqkvb, nullptr, g_q, g_k, g_vt,
                                               4096, 6144, 2048);
  rope_kernel<<<16384, 256, 0, stream>>>(g_q, g_k);
  cast_f32_bf16<<<2048, 256, 0, stream>>>(wproj, wprojb, 4194304 / 8);
  attn_kernel<<<dim3(16, 32), 256, 0, stream>>>(g_q, g_k, g_vt, g_att);
  gemm_bt<0><<<dim3(16, 32), 256, 0, stream>>>(g_att, wprojb, out, nullptr, nullptr,
                                               nullptr, 4096, 2048, 2048);
}

// Round 4
// 281.532 us; speedup vs baseline: 2.4915x; 1.1075x over previous
//
#include <hip/hip_runtime.h>
#include <hip/hip_bf16.h>

typedef __bf16 bf16_t;
typedef __bf16 bf16x8 __attribute__((ext_vector_type(8)));
typedef float f32x4 __attribute__((ext_vector_type(4)));

#define MFMA16(a, b, c) __builtin_amdgcn_mfma_f32_16x16x32_bf16(a, b, c, 0, 0, 0)

__device__ __forceinline__ void async_copy16(const void* g, void* l) {
  __builtin_amdgcn_global_load_lds(
      (const __attribute__((address_space(1))) void*)g,
      (__attribute__((address_space(3))) void*)l, 16, 0, 0);
}

// ---------------- cast f32 -> bf16 (8 elems/thread) ----------------
__global__ void cast_f32_bf16(const float* __restrict__ in, bf16_t* __restrict__ out, int n8) {
  int stride = gridDim.x * blockDim.x;
  for (int i = blockIdx.x * blockDim.x + threadIdx.x; i < n8; i += stride) {
    const float* p = in + (size_t)i * 8;
    f32x4 a = *(const f32x4*)p;
    f32x4 b = *(const f32x4*)(p + 4);
    bf16x8 o;
    o[0] = (bf16_t)a[0]; o[1] = (bf16_t)a[1]; o[2] = (bf16_t)a[2]; o[3] = (bf16_t)a[3];
    o[4] = (bf16_t)b[0]; o[5] = (bf16_t)b[1]; o[6] = (bf16_t)b[2]; o[7] = (bf16_t)b[3];
    *(bf16x8*)(out + (size_t)i * 8) = o;
  }
}

// ---------------- GEMM: C[m][n] = sum_k A[m][k] * Bw[n][k] ----------------
// MODE 0: write f32 C row-major [M][N]
// MODE 1: fused epilogue via LDS roundtrip:
//   q/k col-blocks: RoPE applied in-register, contiguous bf16 stores
//   v col-blocks:   LDS-transposed, contiguous V^T stores
template <int MODE>
__global__ __launch_bounds__(256) void gemm_bt(
    const bf16_t* __restrict__ A, const bf16_t* __restrict__ Bw, float* __restrict__ C,
    bf16_t* __restrict__ qo, bf16_t* __restrict__ ko, bf16_t* __restrict__ vto,
    int M, int N, int K) {
  __shared__ bf16_t lds[2][2][128 * 32];  // 32 KB; reused as 128x128 bf16 tile in epilogue
  int tid = threadIdx.x;
  int w = tid >> 6, lane = tid & 63;
  int wm = w >> 1, wn = w & 1;
  int mr = lane & 15, kg = lane >> 4;
  int row0 = blockIdx.y * 128;
  int col0 = blockIdx.x * 128;

  auto stage = [&](int buf, int t) {
#pragma unroll
    for (int it = 0; it < 2; ++it) {
      int chunk = it * 256 + tid;
      int r = chunk >> 2, cb = (chunk & 3) * 8;
      async_copy16(A + (size_t)(row0 + r) * K + t * 32 + cb, &lds[buf][0][chunk * 8]);
    }
#pragma unroll
    for (int it = 0; it < 2; ++it) {
      int chunk = it * 256 + tid;
      int r = chunk >> 2, cb = (chunk & 3) * 8;
      async_copy16(Bw + (size_t)(col0 + r) * K + t * 32 + cb, &lds[buf][1][chunk * 8]);
    }
  };

  f32x4 zero = {0.f, 0.f, 0.f, 0.f};
  f32x4 acc[4][4];
#pragma unroll
  for (int i = 0; i < 4; ++i)
#pragma unroll
    for (int jn = 0; jn < 4; ++jn) acc[i][jn] = zero;

  int nt = K / 32, cur = 0;
  stage(0, 0);
  for (int t = 0; t < nt; ++t) {
    __syncthreads();
    if (t + 1 < nt) stage(cur ^ 1, t + 1);
    const bf16_t* As = &lds[cur][0][0];
    const bf16_t* Bs = &lds[cur][1][0];
    bf16x8 af[4], bfr[4];
#pragma unroll
    for (int i = 0; i < 4; ++i)
      af[i] = *(const bf16x8*)(As + (wm * 64 + i * 16 + mr) * 32 + kg * 8);
#pragma unroll
    for (int i = 0; i < 4; ++i)
      bfr[i] = *(const bf16x8*)(Bs + (wn * 64 + i * 16 + mr) * 32 + kg * 8);
#pragma unroll
    for (int i = 0; i < 4; ++i)
#pragma unroll
      for (int jn = 0; jn < 4; ++jn)
        acc[i][jn] = MFMA16(af[i], bfr[jn], acc[i][jn]);
    cur ^= 1;
  }

  if (MODE == 0) {
#pragma unroll
    for (int i = 0; i < 4; ++i)
#pragma unroll
      for (int jn = 0; jn < 4; ++jn)
#pragma unroll
        for (int jj = 0; jj < 4; ++jj) {
          int row = row0 + wm * 64 + i * 16 + kg * 4 + jj;
          int col = col0 + wn * 64 + jn * 16 + mr;
          C[(size_t)row * N + col] = acc[i][jn][jj];
        }
  } else {
    __syncthreads();  // staging LDS dead; all waves done reading
    char* tb = (char*)&lds[0][0][0];  // 32 KB = 128x128 bf16
    int s = col0 >> 11, h = (col0 >> 7) & 15;
    int b = row0 >> 11, t0 = row0 & 2047;
    if (s < 2) {
      // ---- q/k: write [row][col] swizzled ----
#pragma unroll
      for (int i = 0; i < 4; ++i)
#pragma unroll
        for (int jn = 0; jn < 4; ++jn)
#pragma unroll
          for (int jj = 0; jj < 4; ++jj) {
            int row = wm * 64 + i * 16 + kg * 4 + jj;
            int col = wn * 64 + jn * 16 + mr;
            *(bf16_t*)(tb + row * 256 + ((col * 2) ^ ((row & 7) << 4))) =
                (bf16_t)acc[i][jn][jj];
          }
      __syncthreads();
      // ---- read half-row, apply RoPE, store contiguous ----
      int r = tid >> 1, hh = tid & 1;
      int t = t0 + r;
      const char* rowb = tb + r * 256;
      int sz = (r & 7) << 4;
      bf16_t* dst = (s == 0 ? qo : ko) +
                    ((size_t)((b * 16 + h) * 2048 + t)) * 128 + hh * 64;
      float tf = (float)t;
      const float cinv = -0.20762050593046014f;  // -log2(10000)/64
#pragma unroll
      for (int m = 0; m < 8; ++m) {
        bf16x8 va = *(const bf16x8*)(rowb + ((hh * 128 + m * 16) ^ sz));
        bf16x8 vb = *(const bf16x8*)(rowb + (((hh ^ 1) * 128 + m * 16) ^ sz));
        bf16x8 o;
#pragma unroll
        for (int e = 0; e < 8; ++e) {
          float ang = tf * exp2f((float)(m * 8 + e) * cinv);
          float sv = __sinf(ang), cv = __cosf(ang);
          float x1 = (float)va[e], x2 = (float)vb[e];
          float res = (hh == 0) ? (x1 * cv - x2 * sv) : (x1 * cv + x2 * sv);
          o[e] = (bf16_t)res;
        }
        *(bf16x8*)(dst + m * 8) = o;
      }
    } else {
      // ---- v: write transposed [col][row] swizzled ----
#pragma unroll
      for (int i = 0; i < 4; ++i)
#pragma unroll
        for (int jn = 0; jn < 4; ++jn)
#pragma unroll
          for (int jj = 0; jj < 4; ++jj) {
            int row = wm * 64 + i * 16 + kg * 4 + jj;
            int col = wn * 64 + jn * 16 + mr;
            *(bf16_t*)(tb + col * 256 + ((row * 2) ^ ((col & 7) << 4))) =
                (bf16_t)acc[i][jn][jj];
          }
      __syncthreads();
      // ---- read along t, store V^T contiguous ----
      int d = tid >> 1, tseg = (tid & 1) * 64;
      const char* rowb = tb + d * 256;
      int sz = (d & 7) << 4;
      bf16_t* dst = vto + ((size_t)((b * 16 + h) * 128 + d)) * 2048 + t0 + tseg;
#pragma unroll
      for (int m2 = 0; m2 < 8; ++m2)
        *(bf16x8*)(dst + m2 * 8) = *(const bf16x8*)(rowb + ((tseg * 2 + m2 * 16) ^ sz));
    }
  }
}

// ---------------- causal flash attention (v2) ----------------
// grid (16, B*H): block handles q-tile pair {31-bx, bx} sequentially -> 33 tile-iters each.
// K/V tiles staged once per block in LDS (global_load_lds, double-buffered, XOR-swizzled).
// XCD-chunked role swizzle: each XCD serves 4 heads (K+V = 4MB = one L2).
__global__ __launch_bounds__(256) void attn_kernel(
    const bf16_t* __restrict__ qg, const bf16_t* __restrict__ kgl,
    const bf16_t* __restrict__ vtg, bf16_t* __restrict__ og) {
  __shared__ __align__(16) bf16_t Ks[2][64 * 128];
  __shared__ __align__(16) bf16_t Vs[2][128 * 64];
  __shared__ __align__(16) bf16_t plds[4][1024];
  const int T = 2048;
  int tid = threadIdx.x;
  int w = tid >> 6, lane = tid & 63;
  int mr = lane & 15, kg = lane >> 4;
  int swz = (mr & 7) << 4;

  int L = blockIdx.y * 16 + blockIdx.x;
  int role = (L & 7) * 64 + (L >> 3);
  int bx = role & 15, bh = role >> 4;

  const bf16_t* Q = qg + (size_t)bh * T * 128;
  const bf16_t* K = kgl + (size_t)bh * T * 128;
  const bf16_t* Vt = vtg + (size_t)bh * 128 * T;

  int sb = tid * 16;
  int krl = sb >> 8;
  int kc = (sb & 255) ^ ((krl & 7) << 4);
  size_t ksrc = (size_t)krl * 128 + (kc >> 1);
  int vdl = sb >> 7;
  int vc = (sb & 127) ^ ((vdl & 7) << 4);
  size_t vsrc = (size_t)vdl * 2048 + (vc >> 1);

  auto stage = [&](int buf, int kb) {
#pragma unroll
    for (int it = 0; it < 4; ++it)
      async_copy16(K + (size_t)(kb + it * 16) * 128 + ksrc, &Ks[buf][it * 2048 + tid * 8]);
#pragma unroll
    for (int it = 0; it < 4; ++it)
      async_copy16(Vt + (size_t)it * 65536 + kb + vsrc, &Vs[buf][it * 2048 + tid * 8]);
  };

  const float cscale = 0.12751744f;  // (1/sqrt(128)) * log2(e)
  f32x4 zero = {0.f, 0.f, 0.f, 0.f};
  bf16_t* P = &plds[w][0];
  int b = bh >> 4, h = bh & 15;

#pragma unroll 1
  for (int ph = 0; ph < 2; ++ph) {
    int qb = ph ? bx : (31 - bx);
    int qr0 = qb * 64 + w * 16;
    bf16x8 qf[4];
#pragma unroll
    for (int db = 0; db < 4; ++db)
      qf[db] = *(const bf16x8*)(Q + (size_t)(qr0 + mr) * 128 + db * 32 + kg * 8);

    f32x4 acc[8];
#pragma unroll
    for (int d2 = 0; d2 < 8; ++d2) acc[d2] = zero;
    float mrun[4] = {-1e30f, -1e30f, -1e30f, -1e30f};
    float lrun[4] = {0.f, 0.f, 0.f, 0.f};

    int nj = qb + 1;
    __syncthreads();
    stage(0, 0);
    int cur = 0;
#pragma unroll 1
    for (int j = 0; j < nj; ++j) {
      __syncthreads();
      if (j + 1 < nj) stage(cur ^ 1, (j + 1) * 64);
      const char* KsB = (const char*)&Ks[cur][0];
      const char* VsB = (const char*)&Vs[cur][0];
      int kb = j * 64;
      f32x4 s[4];
#pragma unroll
      for (int ntl = 0; ntl < 4; ++ntl) {
        s[ntl] = zero;
        int rowb = (ntl * 16 + mr) * 256;
#pragma unroll
        for (int db = 0; db < 4; ++db) {
          bf16x8 kf = *(const bf16x8*)(KsB + rowb + ((db * 64 + kg * 16) ^ swz));
          s[ntl] = MFMA16(qf[db], kf, s[ntl]);
        }
      }
      float pvv[4][4];
      float tmax[4] = {-3e38f, -3e38f, -3e38f, -3e38f};
      bool diag = (j == qb);
#pragma unroll
      for (int ntl = 0; ntl < 4; ++ntl)
#pragma unroll
        for (int jj = 0; jj < 4; ++jj) {
          float v = s[ntl][jj] * cscale;
          if (diag && (kb + ntl * 16 + mr) > (qr0 + kg * 4 + jj)) v = -1e30f;
          pvv[ntl][jj] = v;
          tmax[jj] = fmaxf(tmax[jj], v);
        }
#pragma unroll
      for (int m = 1; m < 16; m <<= 1)
#pragma unroll
        for (int jj = 0; jj < 4; ++jj)
          tmax[jj] = fmaxf(tmax[jj], __shfl_xor(tmax[jj], m, 64));
      bool ok = true;
#pragma unroll
      for (int jj = 0; jj < 4; ++jj) ok &= (tmax[jj] <= mrun[jj] + 8.0f);
      if (!__all(ok)) {
#pragma unroll
        for (int jj = 0; jj < 4; ++jj) {
          float mn = fmaxf(mrun[jj], tmax[jj]);
          float corr = __builtin_amdgcn_exp2f(mrun[jj] - mn);
          mrun[jj] = mn;
          lrun[jj] *= corr;
#pragma unroll
          for (int d2 = 0; d2 < 8; ++d2) acc[d2][jj] *= corr;
        }
      }
      float rs[4] = {0.f, 0.f, 0.f, 0.f};
#pragma unroll
      for (int ntl = 0; ntl < 4; ++ntl)
#pragma unroll
        for (int jj = 0; jj < 4; ++jj) {
          float p = __builtin_amdgcn_exp2f(pvv[ntl][jj] - mrun[jj]);
          pvv[ntl][jj] = p;
          rs[jj] += p;
        }
#pragma unroll
      for (int m = 1; m < 16; m <<= 1)
#pragma unroll
        for (int jj = 0; jj < 4; ++jj) rs[jj] += __shfl_xor(rs[jj], m, 64);
#pragma unroll
      for (int jj = 0; jj < 4; ++jj) lrun[jj] += rs[jj];
#pragma unroll
      for (int ntl = 0; ntl < 4; ++ntl)
#pragma unroll
        for (int jj = 0; jj < 4; ++jj) {
          int rr = kg * 4 + jj;
          int cbyte = (mr + ntl * 16) * 2;
          *(bf16_t*)((char*)P + rr * 128 + (cbyte ^ ((rr & 7) << 4))) = (bf16_t)pvv[ntl][jj];
        }
#pragma unroll
      for (int ks = 0; ks < 2; ++ks) {
        int cb = (ks * 32 + kg * 8) * 2;
        bf16x8 pa = *(const bf16x8*)((const char*)P + mr * 128 + (cb ^ ((mr & 7) << 4)));
#pragma unroll
        for (int d2 = 0; d2 < 8; ++d2) {
          bf16x8 vf = *(const bf16x8*)(VsB + (d2 * 16 + mr) * 128 + ((ks * 64 + kg * 16) ^ swz));
          acc[d2] = MFMA16(pa, vf, acc[d2]);
        }
      }
      cur ^= 1;
    }
#pragma unroll
    for (int jj = 0; jj < 4; ++jj) {
      float invl = 1.0f / lrun[jj];
      int t = qr0 + kg * 4 + jj;
      size_t row = (size_t)b * 2048 + h * 128 + (t >> 4);
      bf16_t* orow = og + row * 2048 + (t & 15) * 128;
#pragma unroll
      for (int d2 = 0; d2 < 8; ++d2)
        orow[d2 * 16 + mr] = (bf16_t)(acc[d2][jj] * invl);
    }
  }
}

extern "C" void kernel_launch(void* const* d_in, const int* in_sizes, int n_in,
                              void* d_out, int out_size, void* d_ws, size_t ws_size,
                              hipStream_t stream) {
  const float* x = (const float*)d_in[0];      // [2,2048,2048]
  const float* wqkv = (const float*)d_in[1];   // [6144,2048]
  const float* wproj = (const float*)d_in[2];  // [2048,2048]
  float* out = (float*)d_out;                  // [2,2048,2048]
  char* ws = (char*)d_ws;

  const size_t OFF_WQKV = 16777216;
  const size_t OFF_Q = 41943040;
  const size_t OFF_K = 58720256;
  const size_t OFF_VT = 75497472;

  bf16_t* xb = (bf16_t*)(ws);
  bf16_t* wqkvb = (bf16_t*)(ws + OFF_WQKV);
  bf16_t* g_q = (bf16_t*)(ws + OFF_Q);
  bf16_t* g_k = (bf16_t*)(ws + OFF_K);
  bf16_t* g_vt = (bf16_t*)(ws + OFF_VT);
  bf16_t* g_att = (bf16_t*)(ws);               // alias xb (dead after gemm1)
  bf16_t* wprojb = (bf16_t*)(ws + OFF_WQKV);   // alias wqkvb (dead after gemm1)

  cast_f32_bf16<<<2048, 256, 0, stream>>>(x, xb, 8388608 / 8);
  cast_f32_bf16<<<2048, 256, 0, stream>>>(wqkv, wqkvb, 12582912 / 8);
  // qkv gemm with fused RoPE + V-transpose epilogue
  gemm_bt<1><<<dim3(48, 32), 256, 0, stream>>>(xb, wqkvb, nullptr, g_q, g_k, g_vt,
                                               4096, 6144, 2048);
  cast_f32_bf16<<<2048, 256, 0, stream>>>(wproj, wprojb, 4194304 / 8);
  attn_kernel<<<dim3(16, 32), 256, 0, stream>>>(g_q, g_k, g_vt, g_att);
  gemm_bt<0><<<dim3(16, 32), 256, 0, stream>>>(g_att, wprojb, out, nullptr, nullptr,
                                               nullptr, 4096, 2048, 2048);
}